// Round 8
// baseline (438.527 us; speedup 1.0000x reference)
//
#include <hip/hip_runtime.h>

// out = noised + (2*STD) * noise, STD = 0.05  ->  out = a + 0.1f * b
// N = 64*3*512*512 = 50,331,648 fp32 (n4 = 12,582,912 float4s).
//
// History: R4 grid-stride 154us; R5 x4-unroll+nt 172us (refuted); R6
// exact-cover 1xfloat4/thread 141us @ 4.27 TB/s effective (403MB HBM +
// 201MB L3 in 141us). MLP ruled out by Little's law (44KB/CU in flight vs
// 9KB needed). This round: 2 float4s per thread, straight-line, exact
// cover -- halves wave count (196608 -> 98304) to isolate wave-churn
// overhead. Plain stores (nt refuted in R5).

typedef float fx4 __attribute__((ext_vector_type(4)));

__global__ __launch_bounds__(256) void gaussian_noise_add_kernel(
    const fx4* __restrict__ a,
    const fx4* __restrict__ b,
    fx4* __restrict__ out,
    int n4)
{
    // Block covers 512 contiguous float4s: thread t handles base+t and
    // base+t+256. Both fully coalesced.
    int base = blockIdx.x * 512 + threadIdx.x;
    int i0 = base;
    int i1 = base + 256;
    bool v0 = i0 < n4;
    bool v1 = i1 < n4;
    if (v0 & v1) {
        // Straight-line fast path: all 4 loads issued before any use.
        fx4 a0 = a[i0];
        fx4 a1 = a[i1];
        fx4 b0 = b[i0];
        fx4 b1 = b[i1];
        out[i0] = a0 + 0.1f * b0;
        out[i1] = a1 + 0.1f * b1;
    } else {
        if (v0) out[i0] = a[i0] + 0.1f * b[i0];
        if (v1) out[i1] = a[i1] + 0.1f * b[i1];
    }
}

// Scalar tail kernel (defensive; n is divisible by 4 for this problem).
__global__ void gaussian_noise_tail_kernel(
    const float* __restrict__ a,
    const float* __restrict__ b,
    float* __restrict__ out,
    int start, int n)
{
    int i = start + blockIdx.x * blockDim.x + threadIdx.x;
    if (i < n) out[i] = fmaf(0.1f, b[i], a[i]);
}

extern "C" void kernel_launch(void* const* d_in, const int* in_sizes, int n_in,
                              void* d_out, int out_size, void* d_ws, size_t ws_size,
                              hipStream_t stream)
{
    const float* a = (const float*)d_in[0];   // noised
    const float* b = (const float*)d_in[1];   // noise
    float* out = (float*)d_out;
    int n = out_size;
    int n4 = n / 4;

    const int block = 256;
    // Exact cover, 2 float4s per thread: n4 = 12,582,912 -> 24,576 blocks.
    int grid = (n4 + 512 - 1) / 512;
    if (grid > 0) {
        gaussian_noise_add_kernel<<<grid, block, 0, stream>>>(
            (const fx4*)a, (const fx4*)b, (fx4*)out, n4);
    }

    int tail_start = n4 * 4;
    int tail = n - tail_start;
    if (tail > 0) {
        gaussian_noise_tail_kernel<<<(tail + block - 1) / block, block, 0, stream>>>(
            a, b, out, tail_start, n);
    }
}